// Round 18
// baseline (1546.830 us; speedup 1.0000x reference)
//
#include <hip/hip_runtime.h>
#include <math.h>

using u16 = unsigned short;
using u32 = unsigned int;
typedef _Float16 f16x8 __attribute__((ext_vector_type(8)));
typedef float    f32x4 __attribute__((ext_vector_type(4)));

union F16U { _Float16 h; u16 u; };
__device__ __forceinline__ u16 f2h(float f) { F16U x; x.h = (_Float16)f; return x.u; }
__device__ __forceinline__ float h2f(u16 v) { F16U x; x.u = v; return (float)x.h; }

// async 16B global->LDS (linear LDS dest = wave base + lane*16; per-lane global src)
__device__ __forceinline__ void gl16(const void* g, void* l) {
  __builtin_amdgcn_global_load_lds((const __attribute__((address_space(1))) void*)g,
                                   (__attribute__((address_space(3))) void*)l, 16, 0, 0);
}

// ---------------- producers ----------------

// weights permuted to [co][tap*128+ci], f16
__global__ void k_wperm(const float* __restrict__ w, u16* __restrict__ Wp) {
  int idx = blockIdx.x * 256 + threadIdx.x;
  if (idx < 147456) {
    int co = idx / 1152, r = idx - co * 1152, tap = r >> 7, ci = r & 127;
    Wp[idx] = f2h(w[((size_t)co * 128 + ci) * 9 + tap]);
  }
}

// strided (::2) slices, split into hi/lo f16, stored TRANSPOSED [p][c]
__global__ void k_extract(const float* __restrict__ fi, const float* __restrict__ bi,
                          u16* __restrict__ fh, u16* __restrict__ fl,
                          u16* __restrict__ bh, u16* __restrict__ bl) {
  __shared__ u16 lt[4][64][136];
  int ph = blockIdx.x, t = threadIdx.x;
  for (int it = 0; it < 32; ++it) {
    int idx = it * 256 + t;                 // c*64 + pw
    int c = idx >> 6, pw = idx & 63;
    int src = c * 16384 + (2 * ph) * 128 + 2 * pw;
    float vf = fi[src], vb = bi[src];
    u16 fhi = f2h(vf), flo = f2h(vf - h2f(fhi));
    u16 bhi = f2h(vb), blo = f2h(vb - h2f(bhi));
    lt[0][pw][c] = fhi; lt[1][pw][c] = flo; lt[2][pw][c] = bhi; lt[3][pw][c] = blo;
  }
  __syncthreads();
  for (int it = 0; it < 16; ++it) {
    int g = it * 256 + t;                   // 4 arrays * 64 pw * 16 granules
    int arr = g >> 10, rem = g & 1023, pw = rem >> 4, slot = rem & 15;
    uint4 v = *(const uint4*)&lt[arr][pw][slot * 8];
    u16* o = (arr == 0) ? fh : (arr == 1) ? fl : (arr == 2) ? bh : bl;
    *(uint4*)&o[(size_t)(ph * 64 + pw) * 128 + slot * 8] = v;
  }
}

// norm[l] = ||3x3x128 bs-patch|| from hi/lo transposed arrays; one wave per l
__global__ void k_norm(const u16* __restrict__ bh, const u16* __restrict__ bl,
                       float* __restrict__ nrm) {
  int wid = threadIdx.x >> 6, lane = threadIdx.x & 63;
  int l = blockIdx.x * 4 + wid;
  int lh = l >> 6, lw = l & 63;
  float s = 0.f;
#pragma unroll
  for (int dh = -1; dh <= 1; ++dh)
#pragma unroll
    for (int dw = -1; dw <= 1; ++dw) {
      int y = lh + dh, x = lw + dw;
      if ((u32)y < 64u && (u32)x < 64u) {
        int p = y * 64 + x;
        u32 h2 = *(const u32*)&bh[(size_t)p * 128 + lane * 2];
        u32 l2 = *(const u32*)&bl[(size_t)p * 128 + lane * 2];
        float v0 = h2f((u16)h2) + h2f((u16)l2);
        float v1 = h2f((u16)(h2 >> 16)) + h2f((u16)(l2 >> 16));
        s += v0 * v0 + v1 * v1;
      }
    }
#pragma unroll
  for (int off = 32; off; off >>= 1) s += __shfl_xor(s, off);
  if (lane == 0) nrm[l] = sqrtf(s);
}

// ---------------- R GEMM: split-f16 MFMA, fp32-equivalent; XCD q-panel pinned ----------------
__global__ __launch_bounds__(256) void k_rgemm(const u16* __restrict__ fh, const u16* __restrict__ fl,
                                               const u16* __restrict__ bh, const u16* __restrict__ bl,
                                               float* __restrict__ C) {
  __shared__ u16 lds[4 * 128 * 64];
  u16* Ah = lds; u16* Al = lds + 8192; u16* Bh = lds + 16384; u16* Bl = lds + 24576;
  int t = threadIdx.x, lane = t & 63, wid = t >> 6;
  int wm = (wid >> 1) * 64, wn = (wid & 1) * 64;
  int fr = lane & 15, kb = lane >> 4;
  int b = blockIdx.x;
  int xcd = b & 7, r = b >> 3;
  int by = xcd * 4 + (r & 3), bx = r >> 2;
  int q0 = by * 128, l0 = bx * 128;
  f32x4 acc[4][4] = {};
  for (int kt = 0; kt < 128; kt += 64) {
#pragma unroll
    for (int j = 0; j < 4; ++j) {
      int g = wid * 256 + j * 64 + lane;
      int row = g >> 3, s = (g & 7) ^ (row & 7);
      int co = kt + s * 8;
      size_t ldso = (size_t)(wid * 256 + j * 64) * 8;
      gl16(&fh[(size_t)(q0 + row) * 128 + co], Ah + ldso);
      gl16(&fl[(size_t)(q0 + row) * 128 + co], Al + ldso);
      gl16(&bh[(size_t)(l0 + row) * 128 + co], Bh + ldso);
      gl16(&bl[(size_t)(l0 + row) * 128 + co], Bl + ldso);
    }
    __syncthreads();
#pragma unroll
    for (int kf = 0; kf < 2; ++kf) {
      f16x8 ah[4], al4[4], bh4[4], bl4[4];
#pragma unroll
      for (int mi = 0; mi < 4; ++mi) {
        int row = wm + mi * 16 + fr;
        int off = row * 64 + ((kf * 4 + kb) ^ (row & 7)) * 8;
        ah[mi] = *(const f16x8*)&Ah[off];
        al4[mi] = *(const f16x8*)&Al[off];
      }
#pragma unroll
      for (int ni = 0; ni < 4; ++ni) {
        int row = wn + ni * 16 + fr;
        int off = row * 64 + ((kf * 4 + kb) ^ (row & 7)) * 8;
        bh4[ni] = *(const f16x8*)&Bh[off];
        bl4[ni] = *(const f16x8*)&Bl[off];
      }
#pragma unroll
      for (int mi = 0; mi < 4; ++mi)
#pragma unroll
        for (int ni = 0; ni < 4; ++ni) {
          acc[mi][ni] = __builtin_amdgcn_mfma_f32_16x16x32_f16(ah[mi], bh4[ni], acc[mi][ni], 0, 0, 0);
          acc[mi][ni] = __builtin_amdgcn_mfma_f32_16x16x32_f16(ah[mi], bl4[ni], acc[mi][ni], 0, 0, 0);
          acc[mi][ni] = __builtin_amdgcn_mfma_f32_16x16x32_f16(al4[mi], bh4[ni], acc[mi][ni], 0, 0, 0);
        }
    }
    __syncthreads();
  }
#pragma unroll
  for (int mi = 0; mi < 4; ++mi) {
    int qr = q0 + wm + mi * 16 + kb * 4;
#pragma unroll
    for (int ni = 0; ni < 4; ++ni) {
      int lc = l0 + wn + ni * 16 + fr;
#pragma unroll
      for (int r2 = 0; r2 < 4; ++r2)
        C[(size_t)(qr + r2) * 4096 + lc] = acc[mi][ni][r2];
    }
  }
}

// tap offsets (flat diagonal steps)
__device__ __constant__ int TAPS[9] = {-65, -64, -63, -1, 0, 1, 63, 64, 65};

// ---------------- passA: LDS-staged 9-segment stencil; XCD q-chunk pinned ----------------
// block = (q, part); segment s is contiguous: T1 addr = partbase + s*4097 + x
__global__ __launch_bounds__(256) void k_passA(const float* __restrict__ R, const float* __restrict__ nrm,
                                               float* __restrict__ Y0) {
  __shared__ float seg[9][1032];
  int b = blockIdx.x;
  int xcd = b & 7, r = b >> 3;                 // r in [0,2048)
  int q = xcd * 512 + (r >> 2);
  int part = r & 3;
  int t = threadIdx.x;
  int partbase = q * 4096 + part * 1024;
  // cooperative load: 9 segs x 258 float4 (aligned global, aligned LDS)
  for (int j = t; j < 9 * 258; j += 256) {
    int sg = j / 258, pos = j - sg * 258;
    int s = TAPS[sg];
    int ab = partbase + s * 4097 - (s & 3);    // 16B-aligned
    int a = ab + pos * 4;
    a = a < 0 ? 0 : (a > 16777212 ? 16777212 : a);
    *(float4*)&seg[sg][pos * 4] = *(const float4*)&R[a];
  }
  __syncthreads();
  int l0 = part * 1024 + t * 4;
  int idx0 = q * 4096 + l0;
  int qh = q >> 6, qw = q & 63, lh = l0 >> 6, lw0 = l0 & 63;
  float a0 = 0.f, a1 = 0.f, a2 = 0.f, a3 = 0.f;
#define TAPA(i, dh, dw)                                                                \
  {                                                                                    \
    constexpr int s = (dh) * 64 + (dw);                                                \
    constexpr int rr = s & 3;                                                          \
    bool ok = ((u32)(qh + (dh)) < 64u) && ((u32)(qw + (dw)) < 64u) &&                  \
              ((u32)(lh + (dh)) < 64u);                                                \
    float4 lo = *(const float4*)&seg[i][t * 4];                                        \
    float4 hi = *(const float4*)&seg[i][t * 4 + 4];                                    \
    float xx[8] = {lo.x, lo.y, lo.z, lo.w, hi.x, hi.y, hi.z, hi.w};                    \
    if (ok) {                                                                          \
      if ((u32)(lw0 + 0 + (dw)) < 64u) a0 += xx[rr + 0];                               \
      if ((u32)(lw0 + 1 + (dw)) < 64u) a1 += xx[rr + 1];                               \
      if ((u32)(lw0 + 2 + (dw)) < 64u) a2 += xx[rr + 2];                               \
      if ((u32)(lw0 + 3 + (dw)) < 64u) a3 += xx[rr + 3];                               \
    }                                                                                  \
  }
  TAPA(0, -1, -1) TAPA(1, -1, 0) TAPA(2, -1, 1)
  TAPA(3, 0, -1)  TAPA(4, 0, 0)  TAPA(5, 0, 1)
  TAPA(6, 1, -1)  TAPA(7, 1, 0)  TAPA(8, 1, 1)
#undef TAPA
  float4 nv = *(const float4*)&nrm[l0];
  float4 o;
  o.x = a0 / fmaxf(nv.x, 1e-4f);
  o.y = a1 / fmaxf(nv.y, 1e-4f);
  o.z = a2 / fmaxf(nv.z, 1e-4f);
  o.w = a3 / fmaxf(nv.w, 1e-4f);
  *(float4*)&Y0[idx0] = o;
}

// ---------------- fused passB + row softmax; LDS-staged segments per part ----------------
__global__ __launch_bounds__(256) void k_pbsm(const float* __restrict__ T1, u16* __restrict__ att) {
  __shared__ float seg[9][1032];
  int b = blockIdx.x;
  int q = (b & 7) * 512 + (b >> 3);            // xcd-pinned q
  int t = threadIdx.x;
  int qh = q >> 6;
  bool qok = (qh >= 2 && qh <= 61);
  float v[16];
  for (int p = 0; p < 4; ++p) {
    if (p) __syncthreads();                    // protect LDS reuse across parts
    int partbase = q * 4096 + p * 1024;
    for (int j = t; j < 9 * 258; j += 256) {
      int sg = j / 258, pos = j - sg * 258;
      int s = TAPS[sg];
      int ab = partbase + s * 4097 - (s & 3);
      int a = ab + pos * 4;
      a = a < 0 ? 0 : (a > 16777212 ? 16777212 : a);
      *(float4*)&seg[sg][pos * 4] = *(const float4*)&T1[a];
    }
    __syncthreads();
    int l0 = p * 1024 + t * 4;
    int idx0 = q * 4096 + l0;
    int lh = l0 >> 6;
    float a0 = 0.f, a1 = 0.f, a2 = 0.f, a3 = 0.f;
    if (qok && lh >= 2 && lh <= 61) {
#define TAPB(i, s_)                                                                    \
  {                                                                                    \
    constexpr int s = (s_);                                                            \
    constexpr int rr = s & 3;                                                          \
    float4 lo = *(const float4*)&seg[i][t * 4];                                        \
    float4 hi = *(const float4*)&seg[i][t * 4 + 4];                                    \
    float xx[8] = {lo.x, lo.y, lo.z, lo.w, hi.x, hi.y, hi.z, hi.w};                    \
    a0 += xx[rr + 0]; a1 += xx[rr + 1]; a2 += xx[rr + 2]; a3 += xx[rr + 3];            \
  }
      TAPB(0, -65) TAPB(1, -64) TAPB(2, -63)
      TAPB(3, -1)  TAPB(4, 0)   TAPB(5, 1)
      TAPB(6, 63)  TAPB(7, 64)  TAPB(8, 65)
#undef TAPB
    } else {
      float oe[4];
#pragma unroll
      for (int e = 0; e < 4; ++e) {
        int l = l0 + e;
        int pl = ((l & 63) << 6) | (l >> 6);
        int pq = ((q & 63) << 6) | (q >> 6);
        float acc = 0.f;
#pragma unroll
        for (int e2 = -1; e2 <= 1; ++e2) {
          int pa = pl + e2, pb = pq + e2;
          if ((u32)pa < 4096u && (u32)pb < 4096u) {
            int a = ((pa & 63) << 6) | (pa >> 6);
            int bq = ((pb & 63) << 6) | (pb >> 6);
#pragma unroll
            for (int e1 = -1; e1 <= 1; ++e1) {
              int aa = a + e1, bb = bq + e1;
              if ((u32)aa < 4096u && (u32)bb < 4096u) acc += T1[(size_t)bb * 4096 + aa];
            }
          }
        }
        oe[e] = acc;
      }
      a0 = oe[0]; a1 = oe[1]; a2 = oe[2]; a3 = oe[3];
    }
    v[p * 4 + 0] = a0; v[p * 4 + 1] = a1; v[p * 4 + 2] = a2; v[p * 4 + 3] = a3;
  }
  // row softmax (SCALE=10)
  float m = -3.4e38f;
#pragma unroll
  for (int i = 0; i < 16; ++i) m = fmaxf(m, v[i]);
#pragma unroll
  for (int off = 32; off; off >>= 1) m = fmaxf(m, __shfl_xor(m, off));
  __shared__ float redm[4], reds[4];
  int wid = t >> 6, lane = t & 63;
  if (lane == 0) redm[wid] = m;
  __syncthreads();
  m = fmaxf(fmaxf(redm[0], redm[1]), fmaxf(redm[2], redm[3]));
  float s = 0.f;
#pragma unroll
  for (int i = 0; i < 16; ++i) { v[i] = expf(10.f * (v[i] - m)); s += v[i]; }
#pragma unroll
  for (int off = 32; off; off >>= 1) s += __shfl_xor(s, off);
  if (lane == 0) reds[wid] = s;
  __syncthreads();
  s = reds[0] + reds[1] + reds[2] + reds[3];
  float inv = 1.f / s;
  u16* arow = att + (size_t)q * 4096;
#pragma unroll
  for (int p = 0; p < 4; ++p) {
    union { u16 h[4]; uint2 u; } pk;
    pk.h[0] = f2h(v[p * 4 + 0] * inv); pk.h[1] = f2h(v[p * 4 + 1] * inv);
    pk.h[2] = f2h(v[p * 4 + 2] * inv); pk.h[3] = f2h(v[p * 4 + 3] * inv);
    *(uint2*)&arow[p * 1024 + t * 4] = pk.u;
  }
}

// RWt[m][l] = raw_w[l, c,i,j] (m = c*16+i*4+j), f16; 4 l per thread
__global__ void k_rwt(const float* __restrict__ bi, u16* __restrict__ RWt) {
  int tid = blockIdx.x * 256 + threadIdx.x;       // m*1024 + l/4
  int m = tid >> 10, lq = (tid & 1023) * 4;
  int c = m >> 4, i = (m >> 2) & 3, j = m & 3;
  int y = 2 * (lq >> 6) - 1 + i;
  union { u16 h[4]; uint2 u; } pk;
#pragma unroll
  for (int e = 0; e < 4; ++e) {
    int x = 2 * ((lq + e) & 63) - 1 + j;
    float v = 0.f;
    if ((u32)y < 128u && (u32)x < 128u) v = bi[c * 16384 + y * 128 + x];
    pk.h[e] = f2h(v);
  }
  *(uint2*)&RWt[(size_t)m * 4096 + lq] = pk.u;
}

// ---------------- PV GEMM: double-buffered gl16 + XCD m-panel swizzle ----------------
__global__ __launch_bounds__(256) void k_gemm_pv(const u16* __restrict__ A, const u16* __restrict__ Bt,
                                                 float* __restrict__ C) {
  __shared__ u16 lds[2 * 16384];                 // 2 bufs x (A 16KB + B 16KB)
  int t = threadIdx.x, lane = t & 63, wid = t >> 6;
  int wm = (wid >> 1) * 64, wn = (wid & 1) * 64;
  int fr = lane & 15, kb = lane >> 4;
  int bid = blockIdx.x;
  int my = (bid & 7) * 4 + ((bid >> 3) & 3);     // [0,32)
  int nx = bid >> 5;                              // [0,16)
  int m0 = my * 128, n0 = nx * 128;
  f32x4 acc[4][4] = {};
#define STAGE(buf, kt)                                                                  \
  {                                                                                     \
    u16* lA = lds + (buf) * 16384;                                                      \
    u16* lB = lA + 8192;                                                                \
    _Pragma("unroll")                                                                   \
    for (int j = 0; j < 4; ++j) {                                                       \
      int g = wid * 256 + j * 64 + lane;                                                \
      int row = g >> 3, sw = (g & 7) ^ (row & 7);                                       \
      size_t ldso = (size_t)(wid * 256 + j * 64) * 8;                                   \
      gl16(&A[(size_t)(m0 + row) * 4096 + (kt) + sw * 8], lA + ldso);                   \
      gl16(&Bt[(size_t)(n0 + row) * 4096 + (kt) + sw * 8], lB + ldso);                  \
    }                                                                                   \
  }
  STAGE(0, 0)
  __syncthreads();
  int cur = 0;
  for (int kt = 0; kt < 4096; kt += 64) {
    if (kt + 64 < 4096) STAGE(cur ^ 1, kt + 64)
    u16* la = lds + cur * 16384;
    u16* lb = la + 8192;
#pragma unroll
    for (int ks = 0; ks < 2; ++ks) {
      f16x8 af[4], bfr[4];
#pragma unroll
      for (int mi = 0; mi < 4; ++mi) {
        int row = wm + mi * 16 + fr;
        af[mi] = *(const f16x8*)&la[row * 64 + ((ks * 32 + kb * 8) ^ ((row & 7) << 3))];
      }
#pragma unroll
      for (int ni = 0; ni < 4; ++ni) {
        int row = wn + ni * 16 + fr;
        bfr[ni] = *(const f16x8*)&lb[row * 64 + ((ks * 32 + kb * 8) ^ ((row & 7) << 3))];
      }
#pragma unroll
      for (int mi = 0; mi < 4; ++mi)
#pragma unroll
        for (int ni = 0; ni < 4; ++ni)
          acc[mi][ni] = __builtin_amdgcn_mfma_f32_16x16x32_f16(af[mi], bfr[ni], acc[mi][ni], 0, 0, 0);
    }
    __syncthreads();
    cur ^= 1;
  }
#undef STAGE
#pragma unroll
  for (int mi = 0; mi < 4; ++mi) {
    int mr = m0 + wm + mi * 16 + kb * 4;
#pragma unroll
    for (int ni = 0; ni < 4; ++ni) {
      int nc = n0 + wn + ni * 16 + fr;
#pragma unroll
      for (int r = 0; r < 4; ++r)
        C[(size_t)(mr + r) * 2048 + nc] = acc[mi][ni][r];
    }
  }
}

// stride-2 overlap-add of 4x4 patches, /4 -> HWC f16; XCD-pinned to match gemm_pv m-panels
__global__ void k_overlap(const float* __restrict__ O, u16* __restrict__ Yh) {
  int b = blockIdx.x;
  int xcd = b & 7, r = b >> 3;                   // r in [0,1024)
  int oypair = xcd * 8 + (r & 7);                // [0,64) -> oy in [xcd*16, xcd*16+16)
  int c = r >> 3;                                // [0,128)
  int t = threadIdx.x;
  int idx = c * 16384 + oypair * 256 + t;        // (c, oy, ox)
  int ox = idx & 127, oy = (idx & 16383) >> 7;
  int py = oy + 1, px = ox + 1;
  float s = 0.f;
#pragma unroll
  for (int di = 0; di < 2; ++di) {
    int i = (py & 1) + 2 * di;
    int hs = (py - i) >> 1;
    if ((u32)hs >= 64u) continue;
#pragma unroll
    for (int dj = 0; dj < 2; ++dj) {
      int j = (px & 1) + 2 * dj;
      int wsx = (px - j) >> 1;
      if ((u32)wsx >= 64u) continue;
      s += O[(size_t)(hs * 64 + wsx) * 2048 + c * 16 + i * 4 + j];
    }
  }
  // Yh layout: (y*128+x)*128 + c
  Yh[((size_t)oy * 128 + ox) * 128 + c] = f2h(0.25f * s);
}

// ---------------- conv: HWC f16 in, implicit GEMM, global_load_lds ----------------
template<int OUT_F16>
__global__ __launch_bounds__(256) void k_conv(const u16* __restrict__ In, const u16* __restrict__ Wp,
                                              const float* __restrict__ bias, void* __restrict__ out_,
                                              const u16* __restrict__ zg) {
  __shared__ u16 lds[2 * 128 * 64];
  u16* la = lds; u16* lb = lds + 8192;
  int t = threadIdx.x, lane = t & 63, wid = t >> 6;
  int wm = (wid >> 1) * 64, wn = (wid & 1) * 64;
  int fr = lane & 15, kb = lane >> 4;
  int yrow = blockIdx.x, bidx = blockIdx.y;
  const u16* inH = In + (size_t)bidx * 2097152;
  f32x4 acc[4][4] = {};
  for (int step = 0; step < 18; ++step) {
    int tap = step >> 1, ci0 = (step & 1) * 64;
    int dy = tap / 3, dx = tap - 3 * (tap / 3);
    int y = yrow + dy - 1;
#pragma unroll
    for (int j = 0; j < 4; ++j) {
      int g = wid * 256 + j * 64 + lane;
      int row = g >> 3, s = (g & 7) ^ (row & 7);
      size_t ldso = (size_t)(wid * 256 + j * 64) * 8;
      gl16(&Wp[(size_t)row * 1152 + step * 64 + s * 8], la + ldso);
      int xx = row + dx - 1;
      const u16* src = ((u32)y < 128u && (u32)xx < 128u)
                         ? &inH[((size_t)y * 128 + xx) * 128 + ci0 + s * 8] : zg;
      gl16(src, lb + ldso);
    }
    __syncthreads();
#pragma unroll
    for (int ks = 0; ks < 2; ++ks) {
      f16x8 af[4], bfr[4];
#pragma unroll
      for (int mi = 0; mi < 4; ++mi) {
        int row = wm + mi * 16 + fr;
        af[mi] = *(const f16x8*)&la[row * 64 + ((ks * 32 + kb * 8) ^ ((row & 7) << 3))];
      }
#pragma unroll
      for (int ni = 0; ni < 4; ++ni) {
        int row = wn + ni * 16 + fr;
        bfr[ni] = *(const f16x8*)&lb[row * 64 + ((ks * 32 + kb * 8) ^ ((row & 7) << 3))];
      }
#pragma unroll
      for (int mi = 0; mi < 4; ++mi)
#pragma unroll
        for (int ni = 0; ni < 4; ++ni)
          acc[mi][ni] = __builtin_amdgcn_mfma_f32_16x16x32_f16(af[mi], bfr[ni], acc[mi][ni], 0, 0, 0);
    }
    __syncthreads();
  }
#pragma unroll
  for (int mi = 0; mi < 4; ++mi) {
    int co = wm + mi * 16 + kb * 4;
#pragma unroll
    for (int ni = 0; ni < 4; ++ni) {
      int x = wn + ni * 16 + fr;
      if (OUT_F16) {
        union { u16 h[4]; uint2 v; } pk;
#pragma unroll
        for (int r = 0; r < 4; ++r) {
          float val = acc[mi][ni][r] + bias[co + r];
          val = val > 0.f ? val : expm1f(val);
          pk.h[r] = f2h(val);
        }
        u16* oH = (u16*)out_ + (size_t)bidx * 2097152;
        *(uint2*)&oH[((size_t)yrow * 128 + x) * 128 + co] = pk.v;
      } else {
        float* oF = (float*)out_ + (size_t)bidx * 2097152;
#pragma unroll
        for (int r = 0; r < 4; ++r) {
          float val = acc[mi][ni][r] + bias[co + r];
          val = val > 0.f ? val : expm1f(val);
          oF[(size_t)(co + r) * 16384 + yrow * 128 + x] = val;
        }
      }
    }
  }
}

// ---------------- host ----------------

extern "C" void kernel_launch(void* const* d_in, const int* in_sizes, int n_in,
                              void* d_out, int out_size, void* d_ws, size_t ws_size,
                              hipStream_t stream) {
  const float* f  = (const float*)d_in[0];
  const float* b  = (const float*)d_in[1];
  const float* w1 = (const float*)d_in[2];
  const float* b1 = (const float*)d_in[3];
  const float* w2 = (const float*)d_in[4];
  const float* b2 = (const float*)d_in[5];
  float* out = (float*)d_out;
  char* ws = (char*)d_ws;

  // workspace layout (155,795,456 B total)
  float* S0   = (float*)(ws);                       // 64MB: R, then att overlay [0,32MB)
  float* S1   = (float*)(ws + 67108864);            // 64MB: Y0, then RWt [0,16MB) + O [16,48MB)
  u16*   fsTh = (u16*)(ws + 134217728);             // 1,048,576
  u16*   fsTl = (u16*)(ws + 135266304);             // 1,048,576
  u16*   bsTh = (u16*)(ws + 136314880);             // 1,048,576
  u16*   bsTl = (u16*)(ws + 137363456);             // 1,048,576
  float* nrm  = (float*)(ws + 138412032);           // 16,384
  u16*   Yh   = (u16*)(ws + 138428416);             // 16,777,216 (4 batches HWC f16)
  u16*   Wp1  = (u16*)(ws + 155205632);             // 294,912
  u16*   Wp2  = (u16*)(ws + 155500544);             // 294,912 -> 155,795,456
  u16*   att  = (u16*)S0;                           // [0, 32MB) of S0 (R dead after passA)
  u16*   RWt  = (u16*)S1;                           // [0, 16MB) of S1 (Y0 dead after pbsm)
  float* O    = (float*)(ws + 67108864 + 16777216); // [16MB, 48MB) of S1
  u16*   Z1h  = (u16*)S0;                           // convs run after loop
  u16*   zg   = (u16*)(ws + 50331648);              // 256 B zero guard (S0 + 48MB, untouched)

  k_wperm<<<576, 256, 0, stream>>>(w1, Wp1);
  k_wperm<<<576, 256, 0, stream>>>(w2, Wp2);

  for (int i = 0; i < 4; ++i) {
    const float* fb = f + (size_t)i * 2097152;
    const float* bb = b + (size_t)i * 2097152;
    k_extract<<<64, 256, 0, stream>>>(fb, bb, fsTh, fsTl, bsTh, bsTl);
    k_norm<<<1024, 256, 0, stream>>>(bsTh, bsTl, nrm);
    k_rgemm<<<1024, 256, 0, stream>>>(fsTh, fsTl, bsTh, bsTl, S0);
    k_passA<<<16384, 256, 0, stream>>>(S0, nrm, S1);
    k_pbsm<<<4096, 256, 0, stream>>>(S1, att);
    k_rwt<<<8192, 256, 0, stream>>>(bb, RWt);
    k_gemm_pv<<<512, 256, 0, stream>>>(att, RWt, O);
    k_overlap<<<8192, 256, 0, stream>>>(O, Yh + (size_t)i * 2097152);
  }

  hipMemsetAsync(zg, 0, 256, stream);
  k_conv<1><<<dim3(128, 4), 256, 0, stream>>>(Yh, Wp1, b1, Z1h, zg);
  k_conv<0><<<dim3(128, 4), 256, 0, stream>>>(Z1h, Wp2, b2, out, zg);

  (void)in_sizes; (void)n_in; (void)out_size; (void)ws_size;
}

// Round 19
// 1132.675 us; speedup vs baseline: 1.3656x; 1.3656x over previous
//
#include <hip/hip_runtime.h>
#include <math.h>

using u16 = unsigned short;
using u32 = unsigned int;
typedef _Float16 f16x8 __attribute__((ext_vector_type(8)));
typedef float    f32x4 __attribute__((ext_vector_type(4)));

union F16U { _Float16 h; u16 u; };
__device__ __forceinline__ u16 f2h(float f) { F16U x; x.h = (_Float16)f; return x.u; }
__device__ __forceinline__ float h2f(u16 v) { F16U x; x.u = v; return (float)x.h; }

// async 16B global->LDS (linear LDS dest = wave base + lane*16; per-lane global src)
__device__ __forceinline__ void gl16(const void* g, void* l) {
  __builtin_amdgcn_global_load_lds((const __attribute__((address_space(1))) void*)g,
                                   (__attribute__((address_space(3))) void*)l, 16, 0, 0);
}

// ---------------- producers ----------------

// weights permuted to [co][tap*128+ci], f16
__global__ void k_wperm(const float* __restrict__ w, u16* __restrict__ Wp) {
  int idx = blockIdx.x * 256 + threadIdx.x;
  if (idx < 147456) {
    int co = idx / 1152, r = idx - co * 1152, tap = r >> 7, ci = r & 127;
    Wp[idx] = f2h(w[((size_t)co * 128 + ci) * 9 + tap]);
  }
}

// strided (::2) slices, split into hi/lo f16, stored TRANSPOSED [p][c]
__global__ void k_extract(const float* __restrict__ fi, const float* __restrict__ bi,
                          u16* __restrict__ fh, u16* __restrict__ fl,
                          u16* __restrict__ bh, u16* __restrict__ bl) {
  __shared__ u16 lt[4][64][136];
  int ph = blockIdx.x, t = threadIdx.x;
  for (int it = 0; it < 32; ++it) {
    int idx = it * 256 + t;                 // c*64 + pw
    int c = idx >> 6, pw = idx & 63;
    int src = c * 16384 + (2 * ph) * 128 + 2 * pw;
    float vf = fi[src], vb = bi[src];
    u16 fhi = f2h(vf), flo = f2h(vf - h2f(fhi));
    u16 bhi = f2h(vb), blo = f2h(vb - h2f(bhi));
    lt[0][pw][c] = fhi; lt[1][pw][c] = flo; lt[2][pw][c] = bhi; lt[3][pw][c] = blo;
  }
  __syncthreads();
  for (int it = 0; it < 16; ++it) {
    int g = it * 256 + t;                   // 4 arrays * 64 pw * 16 granules
    int arr = g >> 10, rem = g & 1023, pw = rem >> 4, slot = rem & 15;
    uint4 v = *(const uint4*)&lt[arr][pw][slot * 8];
    u16* o = (arr == 0) ? fh : (arr == 1) ? fl : (arr == 2) ? bh : bl;
    *(uint4*)&o[(size_t)(ph * 64 + pw) * 128 + slot * 8] = v;
  }
}

// norm[l] = ||3x3x128 bs-patch|| from hi/lo transposed arrays; one wave per l
__global__ void k_norm(const u16* __restrict__ bh, const u16* __restrict__ bl,
                       float* __restrict__ nrm) {
  int wid = threadIdx.x >> 6, lane = threadIdx.x & 63;
  int l = blockIdx.x * 4 + wid;
  int lh = l >> 6, lw = l & 63;
  float s = 0.f;
#pragma unroll
  for (int dh = -1; dh <= 1; ++dh)
#pragma unroll
    for (int dw = -1; dw <= 1; ++dw) {
      int y = lh + dh, x = lw + dw;
      if ((u32)y < 64u && (u32)x < 64u) {
        int p = y * 64 + x;
        u32 h2 = *(const u32*)&bh[(size_t)p * 128 + lane * 2];
        u32 l2 = *(const u32*)&bl[(size_t)p * 128 + lane * 2];
        float v0 = h2f((u16)h2) + h2f((u16)l2);
        float v1 = h2f((u16)(h2 >> 16)) + h2f((u16)(l2 >> 16));
        s += v0 * v0 + v1 * v1;
      }
    }
#pragma unroll
  for (int off = 32; off; off >>= 1) s += __shfl_xor(s, off);
  if (lane == 0) nrm[l] = sqrtf(s);
}

// ---------------- R GEMM: split-f16 MFMA, fp32-equivalent; XCD q-panel pinned ----------------
__global__ __launch_bounds__(256) void k_rgemm(const u16* __restrict__ fh, const u16* __restrict__ fl,
                                               const u16* __restrict__ bh, const u16* __restrict__ bl,
                                               float* __restrict__ C) {
  __shared__ u16 lds[4 * 128 * 64];
  u16* Ah = lds; u16* Al = lds + 8192; u16* Bh = lds + 16384; u16* Bl = lds + 24576;
  int t = threadIdx.x, lane = t & 63, wid = t >> 6;
  int wm = (wid >> 1) * 64, wn = (wid & 1) * 64;
  int fr = lane & 15, kb = lane >> 4;
  int b = blockIdx.x;
  int xcd = b & 7, r = b >> 3;
  int by = xcd * 4 + (r & 3), bx = r >> 2;
  int q0 = by * 128, l0 = bx * 128;
  f32x4 acc[4][4] = {};
  for (int kt = 0; kt < 128; kt += 64) {
#pragma unroll
    for (int j = 0; j < 4; ++j) {
      int g = wid * 256 + j * 64 + lane;
      int row = g >> 3, s = (g & 7) ^ (row & 7);
      int co = kt + s * 8;
      size_t ldso = (size_t)(wid * 256 + j * 64) * 8;
      gl16(&fh[(size_t)(q0 + row) * 128 + co], Ah + ldso);
      gl16(&fl[(size_t)(q0 + row) * 128 + co], Al + ldso);
      gl16(&bh[(size_t)(l0 + row) * 128 + co], Bh + ldso);
      gl16(&bl[(size_t)(l0 + row) * 128 + co], Bl + ldso);
    }
    __syncthreads();
#pragma unroll
    for (int kf = 0; kf < 2; ++kf) {
      f16x8 ah[4], al4[4], bh4[4], bl4[4];
#pragma unroll
      for (int mi = 0; mi < 4; ++mi) {
        int row = wm + mi * 16 + fr;
        int off = row * 64 + ((kf * 4 + kb) ^ (row & 7)) * 8;
        ah[mi] = *(const f16x8*)&Ah[off];
        al4[mi] = *(const f16x8*)&Al[off];
      }
#pragma unroll
      for (int ni = 0; ni < 4; ++ni) {
        int row = wn + ni * 16 + fr;
        int off = row * 64 + ((kf * 4 + kb) ^ (row & 7)) * 8;
        bh4[ni] = *(const f16x8*)&Bh[off];
        bl4[ni] = *(const f16x8*)&Bl[off];
      }
#pragma unroll
      for (int mi = 0; mi < 4; ++mi)
#pragma unroll
        for (int ni = 0; ni < 4; ++ni) {
          acc[mi][ni] = __builtin_amdgcn_mfma_f32_16x16x32_f16(ah[mi], bh4[ni], acc[mi][ni], 0, 0, 0);
          acc[mi][ni] = __builtin_amdgcn_mfma_f32_16x16x32_f16(ah[mi], bl4[ni], acc[mi][ni], 0, 0, 0);
          acc[mi][ni] = __builtin_amdgcn_mfma_f32_16x16x32_f16(al4[mi], bh4[ni], acc[mi][ni], 0, 0, 0);
        }
    }
    __syncthreads();
  }
#pragma unroll
  for (int mi = 0; mi < 4; ++mi) {
    int qr = q0 + wm + mi * 16 + kb * 4;
#pragma unroll
    for (int ni = 0; ni < 4; ++ni) {
      int lc = l0 + wn + ni * 16 + fr;
#pragma unroll
      for (int r2 = 0; r2 < 4; ++r2)
        C[(size_t)(qr + r2) * 4096 + lc] = acc[mi][ni][r2];
    }
  }
}

// ---------------- passA: 4-wide stencil, tap loads hoisted (r17 measured form) ----------------
__global__ __launch_bounds__(256, 2) void k_passA(const float* __restrict__ R, const float* __restrict__ nrm,
                                                  float* __restrict__ Y0) {
  int b = blockIdx.x;
  int xcd = b & 7, r = b >> 3;                 // r in [0,2048)
  int q = xcd * 512 + (r >> 2);
  int part = r & 3;
  int l0 = part * 1024 + threadIdx.x * 4;
  int idx0 = q * 4096 + l0;
  int qh = q >> 6, qw = q & 63, lh = l0 >> 6, lw0 = l0 & 63;
  float a0 = 0.f, a1 = 0.f, a2 = 0.f, a3 = 0.f;
#define LDA(i, dh, dw)                                                                 \
  float4 lo##i, hi##i;                                                                 \
  {                                                                                    \
    constexpr int s = (dh) * 64 + (dw);                                                \
    constexpr int rr = s & 3;                                                          \
    int ab = idx0 + s * 4097 - rr;                                                     \
    ab = ab < 0 ? 0 : (ab > 16777208 ? 16777208 : ab);                                 \
    lo##i = *(const float4*)&R[ab];                                                    \
    hi##i = *(const float4*)&R[ab + 4];                                                \
  }
#define ACCA(i, dh, dw)                                                                \
  {                                                                                    \
    constexpr int s = (dh) * 64 + (dw);                                                \
    constexpr int rr = s & 3;                                                          \
    bool ok = ((u32)(qh + (dh)) < 64u) && ((u32)(qw + (dw)) < 64u) &&                  \
              ((u32)(lh + (dh)) < 64u);                                                \
    float xx[8] = {lo##i.x, lo##i.y, lo##i.z, lo##i.w,                                 \
                   hi##i.x, hi##i.y, hi##i.z, hi##i.w};                                \
    if (ok) {                                                                          \
      if ((u32)(lw0 + 0 + (dw)) < 64u) a0 += xx[rr + 0];                               \
      if ((u32)(lw0 + 1 + (dw)) < 64u) a1 += xx[rr + 1];                               \
      if ((u32)(lw0 + 2 + (dw)) < 64u) a2 += xx[rr + 2];                               \
      if ((u32)(lw0 + 3 + (dw)) < 64u) a3 += xx[rr + 3];                               \
    }                                                                                  \
  }
  LDA(0, -1, -1) LDA(1, -1, 0) LDA(2, -1, 1)
  LDA(3, 0, -1)  LDA(4, 0, 0)  LDA(5, 0, 1)
  LDA(6, 1, -1)  LDA(7, 1, 0)  LDA(8, 1, 1)
  ACCA(0, -1, -1) ACCA(1, -1, 0) ACCA(2, -1, 1)
  ACCA(3, 0, -1)  ACCA(4, 0, 0)  ACCA(5, 0, 1)
  ACCA(6, 1, -1)  ACCA(7, 1, 0)  ACCA(8, 1, 1)
#undef LDA
#undef ACCA
  float4 nv = *(const float4*)&nrm[l0];
  float4 o;
  o.x = a0 / fmaxf(nv.x, 1e-4f);
  o.y = a1 / fmaxf(nv.y, 1e-4f);
  o.z = a2 / fmaxf(nv.z, 1e-4f);
  o.w = a3 / fmaxf(nv.w, 1e-4f);
  *(float4*)&Y0[idx0] = o;
}

// ---------------- fused passB + row softmax; 1024 threads, ONE part per thread ----------------
__global__ __launch_bounds__(1024) void k_pbsm(const float* __restrict__ T1, u16* __restrict__ att) {
  int b = blockIdx.x;
  int q = (b & 7) * 512 + (b >> 3);            // xcd-pinned q
  int t = threadIdx.x;
  int p = t >> 8, tl = t & 255;
  int qh = q >> 6;
  bool qok = (qh >= 2 && qh <= 61);
  int l0 = p * 1024 + tl * 4;
  int idx0 = q * 4096 + l0;
  int lh = l0 >> 6;
  float a0 = 0.f, a1 = 0.f, a2 = 0.f, a3 = 0.f;
  if (qok && lh >= 2 && lh <= 61) {
#define TAPB(s_)                                                                       \
  {                                                                                    \
    constexpr int s = (s_);                                                            \
    constexpr int rr = s & 3;                                                          \
    const float* pp = T1 + (idx0 + s * 4097 - rr);                                     \
    float4 lo = *(const float4*)pp, hi = *(const float4*)(pp + 4);                     \
    float xx[8] = {lo.x, lo.y, lo.z, lo.w, hi.x, hi.y, hi.z, hi.w};                    \
    a0 += xx[rr + 0]; a1 += xx[rr + 1]; a2 += xx[rr + 2]; a3 += xx[rr + 3];            \
  }
    TAPB(-65) TAPB(-64) TAPB(-63)
    TAPB(-1)  TAPB(0)   TAPB(1)
    TAPB(63)  TAPB(64)  TAPB(65)
#undef TAPB
  } else {
    float oe[4];
#pragma unroll
    for (int e = 0; e < 4; ++e) {
      int l = l0 + e;
      int pl = ((l & 63) << 6) | (l >> 6);
      int pq = ((q & 63) << 6) | (q >> 6);
      float acc = 0.f;
#pragma unroll
      for (int e2 = -1; e2 <= 1; ++e2) {
        int pa = pl + e2, pb = pq + e2;
        if ((u32)pa < 4096u && (u32)pb < 4096u) {
          int a = ((pa & 63) << 6) | (pa >> 6);
          int bq = ((pb & 63) << 6) | (pb >> 6);
#pragma unroll
          for (int e1 = -1; e1 <= 1; ++e1) {
            int aa = a + e1, bb = bq + e1;
            if ((u32)aa < 4096u && (u32)bb < 4096u) acc += T1[(size_t)bb * 4096 + aa];
          }
        }
      }
      oe[e] = acc;
    }
    a0 = oe[0]; a1 = oe[1]; a2 = oe[2]; a3 = oe[3];
  }
  // row softmax over all 1024 threads (16 waves)
  float m = fmaxf(fmaxf(a0, a1), fmaxf(a2, a3));
#pragma unroll
  for (int off = 32; off; off >>= 1) m = fmaxf(m, __shfl_xor(m, off));
  __shared__ float redm[16], reds[16];
  int wid = t >> 6, lane = t & 63;
  if (lane == 0) redm[wid] = m;
  __syncthreads();
  m = redm[0];
#pragma unroll
  for (int i = 1; i < 16; ++i) m = fmaxf(m, redm[i]);
  float e0 = expf(10.f * (a0 - m)), e1 = expf(10.f * (a1 - m));
  float e2 = expf(10.f * (a2 - m)), e3 = expf(10.f * (a3 - m));
  float s = e0 + e1 + e2 + e3;
#pragma unroll
  for (int off = 32; off; off >>= 1) s += __shfl_xor(s, off);
  if (lane == 0) reds[wid] = s;
  __syncthreads();
  s = reds[0];
#pragma unroll
  for (int i = 1; i < 16; ++i) s += reds[i];
  float inv = 1.f / s;
  union { u16 h[4]; uint2 u; } pk;
  pk.h[0] = f2h(e0 * inv); pk.h[1] = f2h(e1 * inv);
  pk.h[2] = f2h(e2 * inv); pk.h[3] = f2h(e3 * inv);
  *(uint2*)&att[(size_t)q * 4096 + l0] = pk.u;
}

// RWt[m][l] = raw_w[l, c,i,j] (m = c*16+i*4+j), f16; 4 l per thread
__global__ void k_rwt(const float* __restrict__ bi, u16* __restrict__ RWt) {
  int tid = blockIdx.x * 256 + threadIdx.x;       // m*1024 + l/4
  int m = tid >> 10, lq = (tid & 1023) * 4;
  int c = m >> 4, i = (m >> 2) & 3, j = m & 3;
  int y = 2 * (lq >> 6) - 1 + i;
  union { u16 h[4]; uint2 u; } pk;
#pragma unroll
  for (int e = 0; e < 4; ++e) {
    int x = 2 * ((lq + e) & 63) - 1 + j;
    float v = 0.f;
    if ((u32)y < 128u && (u32)x < 128u) v = bi[c * 16384 + y * 128 + x];
    pk.h[e] = f2h(v);
  }
  *(uint2*)&RWt[(size_t)m * 4096 + lq] = pk.u;
}

// ---------------- PV GEMM: double-buffered gl16 + XCD m-panel swizzle ----------------
__global__ __launch_bounds__(256) void k_gemm_pv(const u16* __restrict__ A, const u16* __restrict__ Bt,
                                                 float* __restrict__ C) {
  __shared__ u16 lds[2 * 16384];                 // 2 bufs x (A 16KB + B 16KB)
  int t = threadIdx.x, lane = t & 63, wid = t >> 6;
  int wm = (wid >> 1) * 64, wn = (wid & 1) * 64;
  int fr = lane & 15, kb = lane >> 4;
  int bid = blockIdx.x;
  int my = (bid & 7) * 4 + ((bid >> 3) & 3);     // [0,32)
  int nx = bid >> 5;                              // [0,16)
  int m0 = my * 128, n0 = nx * 128;
  f32x4 acc[4][4] = {};
#define STAGE(buf, kt)                                                                  \
  {                                                                                     \
    u16* lA = lds + (buf) * 16384;                                                      \
    u16* lB = lA + 8192;                                                                \
    _Pragma("unroll")                                                                   \
    for (int j = 0; j < 4; ++j) {                                                       \
      int g = wid * 256 + j * 64 + lane;                                                \
      int row = g >> 3, sw = (g & 7) ^ (row & 7);                                       \
      size_t ldso = (size_t)(wid * 256 + j * 64) * 8;                                   \
      gl16(&A[(size_t)(m0 + row) * 4096 + (kt) + sw * 8], lA + ldso);                   \
      gl16(&Bt[(size_t)(n0 + row) * 4096 + (kt) + sw * 8], lB + ldso);                  \
    }                                                                                   \
  }
  STAGE(0, 0)
  __syncthreads();
  int cur = 0;
  for (int kt = 0; kt < 4096; kt += 64) {
    if (kt + 64 < 4096) STAGE(cur ^ 1, kt + 64)
    u16* la = lds + cur * 16384;
    u16* lb = la + 8192;
#pragma unroll
    for (int ks = 0; ks < 2; ++ks) {
      f16x8 af[4], bfr[4];
#pragma unroll
      for (int mi = 0; mi < 4; ++mi) {
        int row = wm + mi * 16 + fr;
        af[mi] = *(const f16x8*)&la[row * 64 + ((ks * 32 + kb * 8) ^ ((row & 7) << 3))];
      }
#pragma unroll
      for (int ni = 0; ni < 4; ++ni) {
        int row = wn + ni * 16 + fr;
        bfr[ni] = *(const f16x8*)&lb[row * 64 + ((ks * 32 + kb * 8) ^ ((row & 7) << 3))];
      }
#pragma unroll
      for (int mi = 0; mi < 4; ++mi)
#pragma unroll
        for (int ni = 0; ni < 4; ++ni)
          acc[mi][ni] = __builtin_amdgcn_mfma_f32_16x16x32_f16(af[mi], bfr[ni], acc[mi][ni], 0, 0, 0);
    }
    __syncthreads();
    cur ^= 1;
  }
#undef STAGE
#pragma unroll
  for (int mi = 0; mi < 4; ++mi) {
    int mr = m0 + wm + mi * 16 + kb * 4;
#pragma unroll
    for (int ni = 0; ni < 4; ++ni) {
      int nc = n0 + wn + ni * 16 + fr;
#pragma unroll
      for (int r = 0; r < 4; ++r)
        C[(size_t)(mr + r) * 2048 + nc] = acc[mi][ni][r];
    }
  }
}

// stride-2 overlap-add of 4x4 patches, /4 -> HWC f16; XCD-pinned to match gemm_pv m-panels
__global__ void k_overlap(const float* __restrict__ O, u16* __restrict__ Yh) {
  int b = blockIdx.x;
  int xcd = b & 7, r = b >> 3;                   // r in [0,1024)
  int oypair = xcd * 8 + (r & 7);                // [0,64) -> oy in [xcd*16, xcd*16+16)
  int c = r >> 3;                                // [0,128)
  int t = threadIdx.x;
  int idx = c * 16384 + oypair * 256 + t;        // (c, oy, ox)
  int ox = idx & 127, oy = (idx & 16383) >> 7;
  int py = oy + 1, px = ox + 1;
  float s = 0.f;
#pragma unroll
  for (int di = 0; di < 2; ++di) {
    int i = (py & 1) + 2 * di;
    int hs = (py - i) >> 1;
    if ((u32)hs >= 64u) continue;
#pragma unroll
    for (int dj = 0; dj < 2; ++dj) {
      int j = (px & 1) + 2 * dj;
      int wsx = (px - j) >> 1;
      if ((u32)wsx >= 64u) continue;
      s += O[(size_t)(hs * 64 + wsx) * 2048 + c * 16 + i * 4 + j];
    }
  }
  // Yh layout: (y*128+x)*128 + c
  Yh[((size_t)oy * 128 + ox) * 128 + c] = f2h(0.25f * s);
}

// ---------------- conv: HWC f16 in, implicit GEMM, global_load_lds ----------------
template<int OUT_F16>
__global__ __launch_bounds__(256) void k_conv(const u16* __restrict__ In, const u16* __restrict__ Wp,
                                              const float* __restrict__ bias, void* __restrict__ out_,
                                              const u16* __restrict__ zg) {
  __shared__ u16 lds[2 * 128 * 64];
  u16* la = lds; u16* lb = lds + 8192;
  int t = threadIdx.x, lane = t & 63, wid = t >> 6;
  int wm = (wid >> 1) * 64, wn = (wid & 1) * 64;
  int fr = lane & 15, kb = lane >> 4;
  int yrow = blockIdx.x, bidx = blockIdx.y;
  const u16* inH = In + (size_t)bidx * 2097152;
  f32x4 acc[4][4] = {};
  for (int step = 0; step < 18; ++step) {
    int tap = step >> 1, ci0 = (step & 1) * 64;
    int dy = tap / 3, dx = tap - 3 * (tap / 3);
    int y = yrow + dy - 1;
#pragma unroll
    for (int j = 0; j < 4; ++j) {
      int g = wid * 256 + j * 64 + lane;
      int row = g >> 3, s = (g & 7) ^ (row & 7);
      size_t ldso = (size_t)(wid * 256 + j * 64) * 8;
      gl16(&Wp[(size_t)row * 1152 + step * 64 + s * 8], la + ldso);
      int xx = row + dx - 1;
      const u16* src = ((u32)y < 128u && (u32)xx < 128u)
                         ? &inH[((size_t)y * 128 + xx) * 128 + ci0 + s * 8] : zg;
      gl16(src, lb + ldso);
    }
    __syncthreads();
#pragma unroll
    for (int ks = 0; ks < 2; ++ks) {
      f16x8 af[4], bfr[4];
#pragma unroll
      for (int mi = 0; mi < 4; ++mi) {
        int row = wm + mi * 16 + fr;
        af[mi] = *(const f16x8*)&la[row * 64 + ((ks * 32 + kb * 8) ^ ((row & 7) << 3))];
      }
#pragma unroll
      for (int ni = 0; ni < 4; ++ni) {
        int row = wn + ni * 16 + fr;
        bfr[ni] = *(const f16x8*)&lb[row * 64 + ((ks * 32 + kb * 8) ^ ((row & 7) << 3))];
      }
#pragma unroll
      for (int mi = 0; mi < 4; ++mi)
#pragma unroll
        for (int ni = 0; ni < 4; ++ni)
          acc[mi][ni] = __builtin_amdgcn_mfma_f32_16x16x32_f16(af[mi], bfr[ni], acc[mi][ni], 0, 0, 0);
    }
    __syncthreads();
  }
#pragma unroll
  for (int mi = 0; mi < 4; ++mi) {
    int co = wm + mi * 16 + kb * 4;
#pragma unroll
    for (int ni = 0; ni < 4; ++ni) {
      int x = wn + ni * 16 + fr;
      if (OUT_F16) {
        union { u16 h[4]; uint2 v; } pk;
#pragma unroll
        for (int r = 0; r < 4; ++r) {
          float val = acc[mi][ni][r] + bias[co + r];
          val = val > 0.f ? val : expm1f(val);
          pk.h[r] = f2h(val);
        }
        u16* oH = (u16*)out_ + (size_t)bidx * 2097152;
        *(uint2*)&oH[((size_t)yrow * 128 + x) * 128 + co] = pk.v;
      } else {
        float* oF = (float*)out_ + (size_t)bidx * 2097152;
#pragma unroll
        for (int r = 0; r < 4; ++r) {
          float val = acc[mi][ni][r] + bias[co + r];
          val = val > 0.f ? val : expm1f(val);
          oF[(size_t)(co + r) * 16384 + yrow * 128 + x] = val;
        }
      }
    }
  }
}

// ---------------- host ----------------

extern "C" void kernel_launch(void* const* d_in, const int* in_sizes, int n_in,
                              void* d_out, int out_size, void* d_ws, size_t ws_size,
                              hipStream_t stream) {
  const float* f  = (const float*)d_in[0];
  const float* b  = (const float*)d_in[1];
  const float* w1 = (const float*)d_in[2];
  const float* b1 = (const float*)d_in[3];
  const float* w2 = (const float*)d_in[4];
  const float* b2 = (const float*)d_in[5];
  float* out = (float*)d_out;
  char* ws = (char*)d_ws;

  // workspace layout (155,795,456 B total)
  float* S0   = (float*)(ws);                       // 64MB: R, then att overlay [0,32MB)
  float* S1   = (float*)(ws + 67108864);            // 64MB: Y0, then RWt [0,16MB) + O [16,48MB)
  u16*   fsTh = (u16*)(ws + 134217728);             // 1,048,576
  u16*   fsTl = (u16*)(ws + 135266304);             // 1,048,576
  u16*   bsTh = (u16*)(ws + 136314880);             // 1,048,576
  u16*   bsTl = (u16*)(ws + 137363456);             // 1,048,576
  float* nrm  = (float*)(ws + 138412032);           // 16,384
  u16*   Yh   = (u16*)(ws + 138428416);             // 16,777,216 (4 batches HWC f16)
  u16*   Wp1  = (u16*)(ws + 155205632);             // 294,912
  u16*   Wp2  = (u16*)(ws + 155500544);             // 294,912 -> 155,795,456
  u16*   att  = (u16*)S0;                           // [0, 32MB) of S0 (R dead after passA)
  u16*   RWt  = (u16*)S1;                           // [0, 16MB) of S1 (Y0 dead after pbsm)
  float* O    = (float*)(ws + 67108864 + 16777216); // [16MB, 48MB) of S1
  u16*   Z1h  = (u16*)S0;                           // convs run after loop
  u16*   zg   = (u16*)(ws + 50331648);              // 256 B zero guard (S0 + 48MB, untouched)

  k_wperm<<<576, 256, 0, stream>>>(w1, Wp1);
  k_wperm<<<576, 256, 0, stream>>>(w2, Wp2);

  for (int i = 0; i < 4; ++i) {
    const float* fb = f + (size_t)i * 2097152;
    const float* bb = b + (size_t)i * 2097152;
    k_extract<<<64, 256, 0, stream>>>(fb, bb, fsTh, fsTl, bsTh, bsTl);
    k_norm<<<1024, 256, 0, stream>>>(bsTh, bsTl, nrm);
    k_rgemm<<<1024, 256, 0, stream>>>(fsTh, fsTl, bsTh, bsTl, S0);
    k_passA<<<16384, 256, 0, stream>>>(S0, nrm, S1);
    k_pbsm<<<4096, 1024, 0, stream>>>(S1, att);
    k_rwt<<<8192, 256, 0, stream>>>(bb, RWt);
    k_gemm_pv<<<512, 256, 0, stream>>>(att, RWt, O);
    k_overlap<<<8192, 256, 0, stream>>>(O, Yh + (size_t)i * 2097152);
  }

  hipMemsetAsync(zg, 0, 256, stream);
  k_conv<1><<<dim3(128, 4), 256, 0, stream>>>(Yh, Wp1, b1, Z1h, zg);
  k_conv<0><<<dim3(128, 4), 256, 0, stream>>>(Z1h, Wp2, b2, out, zg);

  (void)in_sizes; (void)n_in; (void)out_size; (void)ws_size;
}

// Round 21
// 1057.092 us; speedup vs baseline: 1.4633x; 1.0715x over previous
//
#include <hip/hip_runtime.h>
#include <math.h>

using u16 = unsigned short;
using u32 = unsigned int;
typedef _Float16 f16x8 __attribute__((ext_vector_type(8)));
typedef float    f32x4 __attribute__((ext_vector_type(4)));

union F16U { _Float16 h; u16 u; };
__device__ __forceinline__ u16 f2h(float f) { F16U x; x.h = (_Float16)f; return x.u; }
__device__ __forceinline__ float h2f(u16 v) { F16U x; x.u = v; return (float)x.h; }

// async 16B global->LDS (linear LDS dest = wave base + lane*16; per-lane global src)
__device__ __forceinline__ void gl16(const void* g, void* l) {
  __builtin_amdgcn_global_load_lds((const __attribute__((address_space(1))) void*)g,
                                   (__attribute__((address_space(3))) void*)l, 16, 0, 0);
}

// ---------------- producers ----------------

// weights permuted to [co][tap*128+ci], f16
__global__ void k_wperm(const float* __restrict__ w, u16* __restrict__ Wp) {
  int idx = blockIdx.x * 256 + threadIdx.x;
  if (idx < 147456) {
    int co = idx / 1152, r = idx - co * 1152, tap = r >> 7, ci = r & 127;
    Wp[idx] = f2h(w[((size_t)co * 128 + ci) * 9 + tap]);
  }
}

// strided (::2) slices, split into hi/lo f16, stored TRANSPOSED [p][c]
__global__ void k_extract(const float* __restrict__ fi, const float* __restrict__ bi,
                          u16* __restrict__ fh, u16* __restrict__ fl,
                          u16* __restrict__ bh, u16* __restrict__ bl) {
  __shared__ u16 lt[4][64][136];
  int ph = blockIdx.x, t = threadIdx.x;
  for (int it = 0; it < 32; ++it) {
    int idx = it * 256 + t;                 // c*64 + pw
    int c = idx >> 6, pw = idx & 63;
    int src = c * 16384 + (2 * ph) * 128 + 2 * pw;
    float vf = fi[src], vb = bi[src];
    u16 fhi = f2h(vf), flo = f2h(vf - h2f(fhi));
    u16 bhi = f2h(vb), blo = f2h(vb - h2f(bhi));
    lt[0][pw][c] = fhi; lt[1][pw][c] = flo; lt[2][pw][c] = bhi; lt[3][pw][c] = blo;
  }
  __syncthreads();
  for (int it = 0; it < 16; ++it) {
    int g = it * 256 + t;                   // 4 arrays * 64 pw * 16 granules
    int arr = g >> 10, rem = g & 1023, pw = rem >> 4, slot = rem & 15;
    uint4 v = *(const uint4*)&lt[arr][pw][slot * 8];
    u16* o = (arr == 0) ? fh : (arr == 1) ? fl : (arr == 2) ? bh : bl;
    *(uint4*)&o[(size_t)(ph * 64 + pw) * 128 + slot * 8] = v;
  }
}

// norm[l] = ||3x3x128 bs-patch|| from hi/lo transposed arrays; one wave per l
__global__ void k_norm(const u16* __restrict__ bh, const u16* __restrict__ bl,
                       float* __restrict__ nrm) {
  int wid = threadIdx.x >> 6, lane = threadIdx.x & 63;
  int l = blockIdx.x * 4 + wid;
  int lh = l >> 6, lw = l & 63;
  float s = 0.f;
#pragma unroll
  for (int dh = -1; dh <= 1; ++dh)
#pragma unroll
    for (int dw = -1; dw <= 1; ++dw) {
      int y = lh + dh, x = lw + dw;
      if ((u32)y < 64u && (u32)x < 64u) {
        int p = y * 64 + x;
        u32 h2 = *(const u32*)&bh[(size_t)p * 128 + lane * 2];
        u32 l2 = *(const u32*)&bl[(size_t)p * 128 + lane * 2];
        float v0 = h2f((u16)h2) + h2f((u16)l2);
        float v1 = h2f((u16)(h2 >> 16)) + h2f((u16)(l2 >> 16));
        s += v0 * v0 + v1 * v1;
      }
    }
#pragma unroll
  for (int off = 32; off; off >>= 1) s += __shfl_xor(s, off);
  if (lane == 0) nrm[l] = sqrtf(s);
}

// ---------------- R GEMM: split-f16 MFMA, fp32-equivalent; XCD q-panel pinned ----------------
__global__ __launch_bounds__(256) void k_rgemm(const u16* __restrict__ fh, const u16* __restrict__ fl,
                                               const u16* __restrict__ bh, const u16* __restrict__ bl,
                                               float* __restrict__ C) {
  __shared__ u16 lds[4 * 128 * 64];
  u16* Ah = lds; u16* Al = lds + 8192; u16* Bh = lds + 16384; u16* Bl = lds + 24576;
  int t = threadIdx.x, lane = t & 63, wid = t >> 6;
  int wm = (wid >> 1) * 64, wn = (wid & 1) * 64;
  int fr = lane & 15, kb = lane >> 4;
  int b = blockIdx.x;
  int xcd = b & 7, r = b >> 3;
  int by = xcd * 4 + (r & 3), bx = r >> 2;
  int q0 = by * 128, l0 = bx * 128;
  f32x4 acc[4][4] = {};
  for (int kt = 0; kt < 128; kt += 64) {
#pragma unroll
    for (int j = 0; j < 4; ++j) {
      int g = wid * 256 + j * 64 + lane;
      int row = g >> 3, s = (g & 7) ^ (row & 7);
      int co = kt + s * 8;
      size_t ldso = (size_t)(wid * 256 + j * 64) * 8;
      gl16(&fh[(size_t)(q0 + row) * 128 + co], Ah + ldso);
      gl16(&fl[(size_t)(q0 + row) * 128 + co], Al + ldso);
      gl16(&bh[(size_t)(l0 + row) * 128 + co], Bh + ldso);
      gl16(&bl[(size_t)(l0 + row) * 128 + co], Bl + ldso);
    }
    __syncthreads();
#pragma unroll
    for (int kf = 0; kf < 2; ++kf) {
      f16x8 ah[4], al4[4], bh4[4], bl4[4];
#pragma unroll
      for (int mi = 0; mi < 4; ++mi) {
        int row = wm + mi * 16 + fr;
        int off = row * 64 + ((kf * 4 + kb) ^ (row & 7)) * 8;
        ah[mi] = *(const f16x8*)&Ah[off];
        al4[mi] = *(const f16x8*)&Al[off];
      }
#pragma unroll
      for (int ni = 0; ni < 4; ++ni) {
        int row = wn + ni * 16 + fr;
        int off = row * 64 + ((kf * 4 + kb) ^ (row & 7)) * 8;
        bh4[ni] = *(const f16x8*)&Bh[off];
        bl4[ni] = *(const f16x8*)&Bl[off];
      }
#pragma unroll
      for (int mi = 0; mi < 4; ++mi)
#pragma unroll
        for (int ni = 0; ni < 4; ++ni) {
          acc[mi][ni] = __builtin_amdgcn_mfma_f32_16x16x32_f16(ah[mi], bh4[ni], acc[mi][ni], 0, 0, 0);
          acc[mi][ni] = __builtin_amdgcn_mfma_f32_16x16x32_f16(ah[mi], bl4[ni], acc[mi][ni], 0, 0, 0);
          acc[mi][ni] = __builtin_amdgcn_mfma_f32_16x16x32_f16(al4[mi], bh4[ni], acc[mi][ni], 0, 0, 0);
        }
    }
    __syncthreads();
  }
#pragma unroll
  for (int mi = 0; mi < 4; ++mi) {
    int qr = q0 + wm + mi * 16 + kb * 4;
#pragma unroll
    for (int ni = 0; ni < 4; ++ni) {
      int lc = l0 + wn + ni * 16 + fr;
#pragma unroll
      for (int r2 = 0; r2 < 4; ++r2)
        C[(size_t)(qr + r2) * 4096 + lc] = acc[mi][ni][r2];
    }
  }
}

// ---------------- passA: 4-wide stencil, tap loads hoisted (r17 measured form) ----------------
__global__ __launch_bounds__(256, 2) void k_passA(const float* __restrict__ R, const float* __restrict__ nrm,
                                                  float* __restrict__ Y0) {
  int b = blockIdx.x;
  int xcd = b & 7, r = b >> 3;                 // r in [0,2048)
  int q = xcd * 512 + (r >> 2);
  int part = r & 3;
  int l0 = part * 1024 + threadIdx.x * 4;
  int idx0 = q * 4096 + l0;
  int qh = q >> 6, qw = q & 63, lh = l0 >> 6, lw0 = l0 & 63;
  float a0 = 0.f, a1 = 0.f, a2 = 0.f, a3 = 0.f;
#define LDA(i, dh, dw)                                                                 \
  float4 lo##i, hi##i;                                                                 \
  {                                                                                    \
    constexpr int s = (dh) * 64 + (dw);                                                \
    constexpr int rr = s & 3;                                                          \
    int ab = idx0 + s * 4097 - rr;                                                     \
    ab = ab < 0 ? 0 : (ab > 16777208 ? 16777208 : ab);                                 \
    lo##i = *(const float4*)&R[ab];                                                    \
    hi##i = *(const float4*)&R[ab + 4];                                                \
  }
#define ACCA(i, dh, dw)                                                                \
  {                                                                                    \
    constexpr int s = (dh) * 64 + (dw);                                                \
    constexpr int rr = s & 3;                                                          \
    bool ok = ((u32)(qh + (dh)) < 64u) && ((u32)(qw + (dw)) < 64u) &&                  \
              ((u32)(lh + (dh)) < 64u);                                                \
    float xx[8] = {lo##i.x, lo##i.y, lo##i.z, lo##i.w,                                 \
                   hi##i.x, hi##i.y, hi##i.z, hi##i.w};                                \
    if (ok) {                                                                          \
      if ((u32)(lw0 + 0 + (dw)) < 64u) a0 += xx[rr + 0];                               \
      if ((u32)(lw0 + 1 + (dw)) < 64u) a1 += xx[rr + 1];                               \
      if ((u32)(lw0 + 2 + (dw)) < 64u) a2 += xx[rr + 2];                               \
      if ((u32)(lw0 + 3 + (dw)) < 64u) a3 += xx[rr + 3];                               \
    }                                                                                  \
  }
  LDA(0, -1, -1) LDA(1, -1, 0) LDA(2, -1, 1)
  LDA(3, 0, -1)  LDA(4, 0, 0)  LDA(5, 0, 1)
  LDA(6, 1, -1)  LDA(7, 1, 0)  LDA(8, 1, 1)
  ACCA(0, -1, -1) ACCA(1, -1, 0) ACCA(2, -1, 1)
  ACCA(3, 0, -1)  ACCA(4, 0, 0)  ACCA(5, 0, 1)
  ACCA(6, 1, -1)  ACCA(7, 1, 0)  ACCA(8, 1, 1)
#undef LDA
#undef ACCA
  float4 nv = *(const float4*)&nrm[l0];
  float4 o;
  o.x = a0 / fmaxf(nv.x, 1e-4f);
  o.y = a1 / fmaxf(nv.y, 1e-4f);
  o.z = a2 / fmaxf(nv.z, 1e-4f);
  o.w = a3 / fmaxf(nv.w, 1e-4f);
  *(float4*)&Y0[idx0] = o;
}

// ---------------- fused passB + row softmax; tap loads hoisted per part ----------------
__global__ __launch_bounds__(256, 2) void k_pbsm(const float* __restrict__ T1, u16* __restrict__ att) {
  int b = blockIdx.x;
  int q = (b & 7) * 512 + (b >> 3);            // xcd-pinned q
  int t = threadIdx.x;
  int qh = q >> 6;
  bool qok = (qh >= 2 && qh <= 61);
  float v[16];
#pragma unroll
  for (int p = 0; p < 4; ++p) {
    int l0 = p * 1024 + t * 4;
    int idx0 = q * 4096 + l0;
    int lh = l0 >> 6;
    float a0 = 0.f, a1 = 0.f, a2 = 0.f, a3 = 0.f;
    if (qok && lh >= 2 && lh <= 61) {
#define LDB(i, s_)                                                                     \
  float4 blo##i, bhi##i;                                                               \
  {                                                                                    \
    constexpr int s = (s_);                                                            \
    constexpr int rr = s & 3;                                                          \
    const float* pp = T1 + (idx0 + s * 4097 - rr);                                     \
    blo##i = *(const float4*)pp;                                                       \
    bhi##i = *(const float4*)(pp + 4);                                                 \
  }
#define ACCB(i, s_)                                                                    \
  {                                                                                    \
    constexpr int s = (s_);                                                            \
    constexpr int rr = s & 3;                                                          \
    float xx[8] = {blo##i.x, blo##i.y, blo##i.z, blo##i.w,                             \
                   bhi##i.x, bhi##i.y, bhi##i.z, bhi##i.w};                            \
    a0 += xx[rr + 0]; a1 += xx[rr + 1]; a2 += xx[rr + 2]; a3 += xx[rr + 3];            \
  }
      // issue all 18 loads first, then accumulate in original order
      LDB(0, -65) LDB(1, -64) LDB(2, -63)
      LDB(3, -1)  LDB(4, 0)   LDB(5, 1)
      LDB(6, 63)  LDB(7, 64)  LDB(8, 65)
      ACCB(0, -65) ACCB(1, -64) ACCB(2, -63)
      ACCB(3, -1)  ACCB(4, 0)   ACCB(5, 1)
      ACCB(6, 63)  ACCB(7, 64)  ACCB(8, 65)
#undef LDB
#undef ACCB
    } else {
      float oe[4];
#pragma unroll
      for (int e = 0; e < 4; ++e) {
        int l = l0 + e;
        int pl = ((l & 63) << 6) | (l >> 6);
        int pq = ((q & 63) << 6) | (q >> 6);
        float acc = 0.f;
#pragma unroll
        for (int e2 = -1; e2 <= 1; ++e2) {
          int pa = pl + e2, pb = pq + e2;
          if ((u32)pa < 4096u && (u32)pb < 4096u) {
            int a = ((pa & 63) << 6) | (pa >> 6);
            int bq = ((pb & 63) << 6) | (pb >> 6);
#pragma unroll
            for (int e1 = -1; e1 <= 1; ++e1) {
              int aa = a + e1, bb = bq + e1;
              if ((u32)aa < 4096u && (u32)bb < 4096u) acc += T1[(size_t)bb * 4096 + aa];
            }
          }
        }
        oe[e] = acc;
      }
      a0 = oe[0]; a1 = oe[1]; a2 = oe[2]; a3 = oe[3];
    }
    v[p * 4 + 0] = a0; v[p * 4 + 1] = a1; v[p * 4 + 2] = a2; v[p * 4 + 3] = a3;
  }
  // row softmax (SCALE=10)
  float m = -3.4e38f;
#pragma unroll
  for (int i = 0; i < 16; ++i) m = fmaxf(m, v[i]);
#pragma unroll
  for (int off = 32; off; off >>= 1) m = fmaxf(m, __shfl_xor(m, off));
  __shared__ float redm[4], reds[4];
  int wid = t >> 6, lane = t & 63;
  if (lane == 0) redm[wid] = m;
  __syncthreads();
  m = fmaxf(fmaxf(redm[0], redm[1]), fmaxf(redm[2], redm[3]));
  float s = 0.f;
#pragma unroll
  for (int i = 0; i < 16; ++i) { v[i] = expf(10.f * (v[i] - m)); s += v[i]; }
#pragma unroll
  for (int off = 32; off; off >>= 1) s += __shfl_xor(s, off);
  if (lane == 0) reds[wid] = s;
  __syncthreads();
  s = reds[0] + reds[1] + reds[2] + reds[3];
  float inv = 1.f / s;
  u16* arow = att + (size_t)q * 4096;
#pragma unroll
  for (int p = 0; p < 4; ++p) {
    union { u16 h[4]; uint2 u; } pk;
    pk.h[0] = f2h(v[p * 4 + 0] * inv); pk.h[1] = f2h(v[p * 4 + 1] * inv);
    pk.h[2] = f2h(v[p * 4 + 2] * inv); pk.h[3] = f2h(v[p * 4 + 3] * inv);
    *(uint2*)&arow[p * 1024 + t * 4] = pk.u;
  }
}

// RWt[m][l] = raw_w[l, c,i,j] (m = c*16+i*4+j), f16; 4 l per thread
__global__ void k_rwt(const float* __restrict__ bi, u16* __restrict__ RWt) {
  int tid = blockIdx.x * 256 + threadIdx.x;       // m*1024 + l/4
  int m = tid >> 10, lq = (tid & 1023) * 4;
  int c = m >> 4, i = (m >> 2) & 3, j = m & 3;
  int y = 2 * (lq >> 6) - 1 + i;
  union { u16 h[4]; uint2 u; } pk;
#pragma unroll
  for (int e = 0; e < 4; ++e) {
    int x = 2 * ((lq + e) & 63) - 1 + j;
    float v = 0.f;
    if ((u32)y < 128u && (u32)x < 128u) v = bi[c * 16384 + y * 128 + x];
    pk.h[e] = f2h(v);
  }
  *(uint2*)&RWt[(size_t)m * 4096 + lq] = pk.u;
}

// ---------------- PV GEMM: double-buffered gl16 + XCD m-panel swizzle ----------------
__global__ __launch_bounds__(256) void k_gemm_pv(const u16* __restrict__ A, const u16* __restrict__ Bt,
                                                 float* __restrict__ C) {
  __shared__ u16 lds[2 * 16384];                 // 2 bufs x (A 16KB + B 16KB)
  int t = threadIdx.x, lane = t & 63, wid = t >> 6;
  int wm = (wid >> 1) * 64, wn = (wid & 1) * 64;
  int fr = lane & 15, kb = lane >> 4;
  int bid = blockIdx.x;
  int my = (bid & 7) * 4 + ((bid >> 3) & 3);     // [0,32)
  int nx = bid >> 5;                              // [0,16)
  int m0 = my * 128, n0 = nx * 128;
  f32x4 acc[4][4] = {};
#define STAGE(buf, kt)                                                                  \
  {                                                                                     \
    u16* lA = lds + (buf) * 16384;                                                      \
    u16* lB = lA + 8192;                                                                \
    _Pragma("unroll")                                                                   \
    for (int j = 0; j < 4; ++j) {                                                       \
      int g = wid * 256 + j * 64 + lane;                                                \
      int row = g >> 3, sw = (g & 7) ^ (row & 7);                                       \
      size_t ldso = (size_t)(wid * 256 + j * 64) * 8;                                   \
      gl16(&A[(size_t)(m0 + row) * 4096 + (kt) + sw * 8], lA + ldso);                   \
      gl16(&Bt[(size_t)(n0 + row) * 4096 + (kt) + sw * 8], lB + ldso);                  \
    }                                                                                   \
  }
  STAGE(0, 0)
  __syncthreads();
  int cur = 0;
  for (int kt = 0; kt < 4096; kt += 64) {
    if (kt + 64 < 4096) STAGE(cur ^ 1, kt + 64)
    u16* la = lds + cur * 16384;
    u16* lb = la + 8192;
#pragma unroll
    for (int ks = 0; ks < 2; ++ks) {
      f16x8 af[4], bfr[4];
#pragma unroll
      for (int mi = 0; mi < 4; ++mi) {
        int row = wm + mi * 16 + fr;
        af[mi] = *(const f16x8*)&la[row * 64 + ((ks * 32 + kb * 8) ^ ((row & 7) << 3))];
      }
#pragma unroll
      for (int ni = 0; ni < 4; ++ni) {
        int row = wn + ni * 16 + fr;
        bfr[ni] = *(const f16x8*)&lb[row * 64 + ((ks * 32 + kb * 8) ^ ((row & 7) << 3))];
      }
#pragma unroll
      for (int mi = 0; mi < 4; ++mi)
#pragma unroll
        for (int ni = 0; ni < 4; ++ni)
          acc[mi][ni] = __builtin_amdgcn_mfma_f32_16x16x32_f16(af[mi], bfr[ni], acc[mi][ni], 0, 0, 0);
    }
    __syncthreads();
    cur ^= 1;
  }
#undef STAGE
#pragma unroll
  for (int mi = 0; mi < 4; ++mi) {
    int mr = m0 + wm + mi * 16 + kb * 4;
#pragma unroll
    for (int ni = 0; ni < 4; ++ni) {
      int nc = n0 + wn + ni * 16 + fr;
#pragma unroll
      for (int r = 0; r < 4; ++r)
        C[(size_t)(mr + r) * 2048 + nc] = acc[mi][ni][r];
    }
  }
}

// stride-2 overlap-add of 4x4 patches, /4 -> HWC f16; XCD-pinned to match gemm_pv m-panels
__global__ void k_overlap(const float* __restrict__ O, u16* __restrict__ Yh) {
  int b = blockIdx.x;
  int xcd = b & 7, r = b >> 3;                   // r in [0,1024)
  int oypair = xcd * 8 + (r & 7);                // [0,64) -> oy in [xcd*16, xcd*16+16)
  int c = r >> 3;                                // [0,128)
  int t = threadIdx.x;
  int idx = c * 16384 + oypair * 256 + t;        // (c, oy, ox)
  int ox = idx & 127, oy = (idx & 16383) >> 7;
  int py = oy + 1, px = ox + 1;
  float s = 0.f;
#pragma unroll
  for (int di = 0; di < 2; ++di) {
    int i = (py & 1) + 2 * di;
    int hs = (py - i) >> 1;
    if ((u32)hs >= 64u) continue;
#pragma unroll
    for (int dj = 0; dj < 2; ++dj) {
      int j = (px & 1) + 2 * dj;
      int wsx = (px - j) >> 1;
      if ((u32)wsx >= 64u) continue;
      s += O[(size_t)(hs * 64 + wsx) * 2048 + c * 16 + i * 4 + j];
    }
  }
  // Yh layout: (y*128+x)*128 + c
  Yh[((size_t)oy * 128 + ox) * 128 + c] = f2h(0.25f * s);
}

// ---------------- conv: HWC f16 in, implicit GEMM, global_load_lds ----------------
template<int OUT_F16>
__global__ __launch_bounds__(256) void k_conv(const u16* __restrict__ In, const u16* __restrict__ Wp,
                                              const float* __restrict__ bias, void* __restrict__ out_,
                                              const u16* __restrict__ zg) {
  __shared__ u16 lds[2 * 128 * 64];
  u16* la = lds; u16* lb = lds + 8192;
  int t = threadIdx.x, lane = t & 63, wid = t >> 6;
  int wm = (wid >> 1) * 64, wn = (wid & 1) * 64;
  int fr = lane & 15, kb = lane >> 4;
  int yrow = blockIdx.x, bidx = blockIdx.y;
  const u16* inH = In + (size_t)bidx * 2097152;
  f32x4 acc[4][4] = {};
  for (int step = 0; step < 18; ++step) {
    int tap = step >> 1, ci0 = (step & 1) * 64;
    int dy = tap / 3, dx = tap - 3 * (tap / 3);
    int y = yrow + dy - 1;
#pragma unroll
    for (int j = 0; j < 4; ++j) {
      int g = wid * 256 + j * 64 + lane;
      int row = g >> 3, s = (g & 7) ^ (row & 7);
      size_t ldso = (size_t)(wid * 256 + j * 64) * 8;
      gl16(&Wp[(size_t)row * 1152 + step * 64 + s * 8], la + ldso);
      int xx = row + dx - 1;
      const u16* src = ((u32)y < 128u && (u32)xx < 128u)
                         ? &inH[((size_t)y * 128 + xx) * 128 + ci0 + s * 8] : zg;
      gl16(src, lb + ldso);
    }
    __syncthreads();
#pragma unroll
    for (int ks = 0; ks < 2; ++ks) {
      f16x8 af[4], bfr[4];
#pragma unroll
      for (int mi = 0; mi < 4; ++mi) {
        int row = wm + mi * 16 + fr;
        af[mi] = *(const f16x8*)&la[row * 64 + ((ks * 32 + kb * 8) ^ ((row & 7) << 3))];
      }
#pragma unroll
      for (int ni = 0; ni < 4; ++ni) {
        int row = wn + ni * 16 + fr;
        bfr[ni] = *(const f16x8*)&lb[row * 64 + ((ks * 32 + kb * 8) ^ ((row & 7) << 3))];
      }
#pragma unroll
      for (int mi = 0; mi < 4; ++mi)
#pragma unroll
        for (int ni = 0; ni < 4; ++ni)
          acc[mi][ni] = __builtin_amdgcn_mfma_f32_16x16x32_f16(af[mi], bfr[ni], acc[mi][ni], 0, 0, 0);
    }
    __syncthreads();
  }
#pragma unroll
  for (int mi = 0; mi < 4; ++mi) {
    int co = wm + mi * 16 + kb * 4;
#pragma unroll
    for (int ni = 0; ni < 4; ++ni) {
      int x = wn + ni * 16 + fr;
      if (OUT_F16) {
        union { u16 h[4]; uint2 v; } pk;
#pragma unroll
        for (int r = 0; r < 4; ++r) {
          float val = acc[mi][ni][r] + bias[co + r];
          val = val > 0.f ? val : expm1f(val);
          pk.h[r] = f2h(val);
        }
        u16* oH = (u16*)out_ + (size_t)bidx * 2097152;
        *(uint2*)&oH[((size_t)yrow * 128 + x) * 128 + co] = pk.v;
      } else {
        float* oF = (float*)out_ + (size_t)bidx * 2097152;
#pragma unroll
        for (int r = 0; r < 4; ++r) {
          float val = acc[mi][ni][r] + bias[co + r];
          val = val > 0.f ? val : expm1f(val);
          oF[(size_t)(co + r) * 16384 + yrow * 128 + x] = val;
        }
      }
    }
  }
}

// ---------------- host ----------------

extern "C" void kernel_launch(void* const* d_in, const int* in_sizes, int n_in,
                              void* d_out, int out_size, void* d_ws, size_t ws_size,
                              hipStream_t stream) {
  const float* f  = (const float*)d_in[0];
  const float* b  = (const float*)d_in[1];
  const float* w1 = (const float*)d_in[2];
  const float* b1 = (const float*)d_in[3];
  const float* w2 = (const float*)d_in[4];
  const float* b2 = (const float*)d_in[5];
  float* out = (float*)d_out;
  char* ws = (char*)d_ws;

  // workspace layout (155,795,456 B total)
  float* S0   = (float*)(ws);                       // 64MB: R, then att overlay [0,32MB)
  float* S1   = (float*)(ws + 67108864);            // 64MB: Y0, then RWt [0,16MB) + O [16,48MB)
  u16*   fsTh = (u16*)(ws + 134217728);             // 1,048,576
  u16*   fsTl = (u16*)(ws + 135266304);             // 1,048,576
  u16*   bsTh = (u16*)(ws + 136314880);             // 1,048,576
  u16*   bsTl = (u16*)(ws + 137363456);             // 1,048,576
  float* nrm  = (float*)(ws + 138412032);           // 16,384
  u16*   Yh   = (u16*)(ws + 138428416);             // 16,777,216 (4 batches HWC f16)
  u16*   Wp1  = (u16*)(ws + 155205632);             // 294,912
  u16*   Wp2  = (u16*)(ws + 155500544);             // 294,912 -> 155,795,456
  u16*   att  = (u16*)S0;                           // [0, 32MB) of S0 (R dead after passA)
  u16*   RWt  = (u16*)S1;                           // [0, 16MB) of S1 (Y0 dead after pbsm)
  float* O    = (float*)(ws + 67108864 + 16777216); // [16MB, 48MB) of S1
  u16*   Z1h  = (u16*)S0;                           // convs run after loop
  u16*   zg   = (u16*)(ws + 50331648);              // 256 B zero guard (S0 + 48MB, untouched)

  k_wperm<<<576, 256, 0, stream>>>(w1, Wp1);
  k_wperm<<<576, 256, 0, stream>>>(w2, Wp2);

  for (int i = 0; i < 4; ++i) {
    const float* fb = f + (size_t)i * 2097152;
    const float* bb = b + (size_t)i * 2097152;
    k_extract<<<64, 256, 0, stream>>>(fb, bb, fsTh, fsTl, bsTh, bsTl);
    k_norm<<<1024, 256, 0, stream>>>(bsTh, bsTl, nrm);
    k_rgemm<<<1024, 256, 0, stream>>>(fsTh, fsTl, bsTh, bsTl, S0);
    k_passA<<<16384, 256, 0, stream>>>(S0, nrm, S1);
    k_pbsm<<<4096, 256, 0, stream>>>(S1, att);
    k_rwt<<<8192, 256, 0, stream>>>(bb, RWt);
    k_gemm_pv<<<512, 256, 0, stream>>>(att, RWt, O);
    k_overlap<<<8192, 256, 0, stream>>>(O, Yh + (size_t)i * 2097152);
  }

  hipMemsetAsync(zg, 0, 256, stream);
  k_conv<1><<<dim3(128, 4), 256, 0, stream>>>(Yh, Wp1, b1, Z1h, zg);
  k_conv<0><<<dim3(128, 4), 256, 0, stream>>>(Z1h, Wp2, b2, out, zg);

  (void)in_sizes; (void)n_in; (void)out_size; (void)ws_size;
}